// Round 6
// baseline (130.532 us; speedup 1.0000x reference)
//
#include <hip/hip_runtime.h>
#include <cfloat>

#define K_CODES 256
#define D_DIM 5
#define T_DIM 16384
#define B_DIM 32
#define NPTS (B_DIM * T_DIM)     // 524288 points
#define NELEM (NPTS * D_DIM)     // 2621440 elements
#define PPT 4                    // consecutive points (t) per thread
#define BLK 256

// Codebook: f32 [K][8] = e0..e4, esq(np-rounding), pad, pad. Zero loss acc.
// esq = np.sum(e**2, axis=0): squares rounded individually, then sequential
// ascending adds — NO fma (use explicit rounding intrinsics).
__global__ void vq_prep(const float* __restrict__ e, float* __restrict__ cb,
                        double* __restrict__ acc) {
    int k = threadIdx.x;
    float v0 = e[0 * K_CODES + k];
    float v1 = e[1 * K_CODES + k];
    float v2 = e[2 * K_CODES + k];
    float v3 = e[3 * K_CODES + k];
    float v4 = e[4 * K_CODES + k];
    float esq = __fmul_rn(v0, v0);
    esq = __fadd_rn(esq, __fmul_rn(v1, v1));
    esq = __fadd_rn(esq, __fmul_rn(v2, v2));
    esq = __fadd_rn(esq, __fmul_rn(v3, v3));
    esq = __fadd_rn(esq, __fmul_rn(v4, v4));
    float* p = cb + 8 * k;
    p[0] = v0; p[1] = v1; p[2] = v2; p[3] = v3;
    p[4] = v4; p[5] = esq; p[6] = 0.f; p[7] = 0.f;
    if (k == 0) *acc = 0.0;
}

__global__ __launch_bounds__(BLK) void vq_main(const float* __restrict__ x,
                                               const float* __restrict__ cb,
                                               float* __restrict__ out,
                                               double* __restrict__ acc) {
    const int g = blockIdx.x * BLK + threadIdx.x;
    const int p0 = g * PPT;            // 4 consecutive t within one b
    const int b = p0 >> 14;            // p0 / T_DIM
    const int t = p0 & (T_DIM - 1);    // p0 % T_DIM (multiple of 4)
    const float* xp = x + (b * D_DIM) * T_DIM + t;

    float xv[PPT][D_DIM];
    float xsq[PPT];
    float best[PPT];
    int bidx[PPT];

    #pragma unroll
    for (int d = 0; d < D_DIM; d++) {
        float4 v = *(const float4*)(xp + d * T_DIM);  // coalesced 16 B/lane
        xv[0][d] = v.x; xv[1][d] = v.y; xv[2][d] = v.z; xv[3][d] = v.w;
    }
    // np: tmp = x**2 (each square ROUNDED), then sequential ascending adds.
    #pragma unroll
    for (int i = 0; i < PPT; i++) {
        float s = __fmul_rn(xv[i][0], xv[i][0]);
        s = __fadd_rn(s, __fmul_rn(xv[i][1], xv[i][1]));
        s = __fadd_rn(s, __fmul_rn(xv[i][2], xv[i][2]));
        s = __fadd_rn(s, __fmul_rn(xv[i][3], xv[i][3]));
        s = __fadd_rn(s, __fmul_rn(xv[i][4], xv[i][4]));
        xsq[i] = s;
        best[i] = FLT_MAX;
        bidx[i] = 0;
    }

    // np matmul (sgemm): single-accumulator ascending-k FMA chain, acc starts
    // at 0 (first step == rounded product). dist replicates numpy's
    // left-to-right (xsq - 2*dot) + esq, one rounding per op.
    #pragma unroll 2
    for (int k = 0; k < K_CODES; k++) {
        const float* c = cb + 8 * k;   // wave-uniform -> scalar loads
        float c0 = c[0], c1 = c[1], c2 = c[2], c3 = c[3], c4 = c[4];
        float esq = c[5];
        #pragma unroll
        for (int i = 0; i < PPT; i++) {
            float dot = __fmul_rn(xv[i][0], c0);
            dot = __fmaf_rn(xv[i][1], c1, dot);
            dot = __fmaf_rn(xv[i][2], c2, dot);
            dot = __fmaf_rn(xv[i][3], c3, dot);
            dot = __fmaf_rn(xv[i][4], c4, dot);
            float dist = __fadd_rn(__fsub_rn(xsq[i], __fadd_rn(dot, dot)), esq);
            if (dist < best[i]) { best[i] = dist; bidx[i] = k; }  // np first-min
        }
    }

    // Gather selected codewords (raw fp32), write coalesced float4 per d;
    // loss accumulated in fp32 per thread (f64-reduced across threads).
    float qr[PPT][D_DIM];
    float ls = 0.f;
    #pragma unroll
    for (int i = 0; i < PPT; i++) {
        const float* c = cb + 8 * bidx[i];  // 8 KB table, L1-hot
        #pragma unroll
        for (int d = 0; d < D_DIM; d++) {
            float qv = c[d];
            qr[i][d] = qv;
            float df = xv[i][d] - qv;
            ls += df * df;
        }
    }
    float* op = out + (b * D_DIM) * T_DIM + t;
    #pragma unroll
    for (int d = 0; d < D_DIM; d++) {
        float4 o;
        o.x = qr[0][d]; o.y = qr[1][d]; o.z = qr[2][d]; o.w = qr[3][d];
        *(float4*)(op + d * T_DIM) = o;   // straight-through output == q
    }

    // wave reduce (64 lanes) -> block reduce -> one f64 atomic per block
    #pragma unroll
    for (int off = 32; off > 0; off >>= 1) ls += __shfl_down(ls, off, 64);
    __shared__ float wsum[BLK / 64];
    int lane = threadIdx.x & 63;
    int wid = threadIdx.x >> 6;
    if (lane == 0) wsum[wid] = ls;
    __syncthreads();
    if (threadIdx.x == 0) {
        float tot = 0.f;
        #pragma unroll
        for (int w = 0; w < BLK / 64; w++) tot += wsum[w];
        atomicAdd(acc, (double)tot);
    }
}

__global__ void vq_finalize(const double* __restrict__ acc,
                            float* __restrict__ out) {
    float loss = (float)(*acc / (double)NELEM);
    out[NELEM] = loss;      // dictionary_loss
    out[NELEM + 1] = loss;  // commitment_loss (identical forward value)
}

extern "C" void kernel_launch(void* const* d_in, const int* in_sizes, int n_in,
                              void* d_out, int out_size, void* d_ws, size_t ws_size,
                              hipStream_t stream) {
    const float* x = (const float*)d_in[0];   // fp32 (B,D,T), raw
    const float* e = (const float*)d_in[1];   // fp32 (D,K), raw
    float* out = (float*)d_out;               // fp32: quantized + 2 losses
    double* acc = (double*)d_ws;              // 8 B
    float* cb = (float*)((char*)d_ws + 64);   // 8 KB packed codebook

    vq_prep<<<1, K_CODES, 0, stream>>>(e, cb, acc);
    vq_main<<<NPTS / (PPT * BLK), BLK, 0, stream>>>(x, cb, out, acc);
    vq_finalize<<<1, 1, 0, stream>>>(acc, out);
}

// Round 7
// 90.301 us; speedup vs baseline: 1.4455x; 1.4455x over previous
//
#include <hip/hip_runtime.h>
#include <cfloat>

#define K_CODES 256
#define D_DIM 5
#define T_DIM 16384
#define B_DIM 32
#define NPTS (B_DIM * T_DIM)     // 524288 points
#define NELEM (NPTS * D_DIM)     // 2621440 elements
#define PPT 4                    // consecutive points (t) per thread
#define BLK 256
#define NBLOCKS (NPTS / (PPT * BLK))  // 512

__global__ __launch_bounds__(BLK) void vq_main(const float* __restrict__ x,
                                               const float* __restrict__ e,
                                               float* __restrict__ out,
                                               double* __restrict__ partials) {
    // ---- per-block codebook prep into LDS (bit-identical to np semantics) ----
    __shared__ float cbs[K_CODES * 8];  // [k][8] = e0..e4, esq, pad, pad
    {
        int k = threadIdx.x;  // BLK == K_CODES
        float v0 = e[0 * K_CODES + k];
        float v1 = e[1 * K_CODES + k];
        float v2 = e[2 * K_CODES + k];
        float v3 = e[3 * K_CODES + k];
        float v4 = e[4 * K_CODES + k];
        // np: e**2 rounds each square, then sequential ascending adds (no fma)
        float esq = __fmul_rn(v0, v0);
        esq = __fadd_rn(esq, __fmul_rn(v1, v1));
        esq = __fadd_rn(esq, __fmul_rn(v2, v2));
        esq = __fadd_rn(esq, __fmul_rn(v3, v3));
        esq = __fadd_rn(esq, __fmul_rn(v4, v4));
        float4* p = (float4*)&cbs[8 * k];
        p[0] = make_float4(v0, v1, v2, v3);
        p[1] = make_float4(v4, esq, 0.f, 0.f);
    }
    __syncthreads();

    // ---- load this thread's 4 points (coalesced float4 per d) ----
    const int g = blockIdx.x * BLK + threadIdx.x;
    const int p0 = g * PPT;
    const int b = p0 >> 14;            // p0 / T_DIM
    const int t = p0 & (T_DIM - 1);    // p0 % T_DIM (multiple of 4)
    const float* xp = x + (b * D_DIM) * T_DIM + t;

    float xv[PPT][D_DIM];
    float xsq[PPT];
    float best[PPT];
    int bidx[PPT];

    #pragma unroll
    for (int d = 0; d < D_DIM; d++) {
        float4 v = *(const float4*)(xp + d * T_DIM);
        xv[0][d] = v.x; xv[1][d] = v.y; xv[2][d] = v.z; xv[3][d] = v.w;
    }
    // np: x**2 rounds each square, then sequential ascending adds (no fma)
    #pragma unroll
    for (int i = 0; i < PPT; i++) {
        float s = __fmul_rn(xv[i][0], xv[i][0]);
        s = __fadd_rn(s, __fmul_rn(xv[i][1], xv[i][1]));
        s = __fadd_rn(s, __fmul_rn(xv[i][2], xv[i][2]));
        s = __fadd_rn(s, __fmul_rn(xv[i][3], xv[i][3]));
        s = __fadd_rn(s, __fmul_rn(xv[i][4], xv[i][4]));
        xsq[i] = s;
        best[i] = FLT_MAX;
        bidx[i] = 0;
    }

    // ---- scan: sgemm-semantics dot (single-acc ascending FMA chain), numpy's
    // left-to-right (xsq - 2*dot) + esq, strict < ascending k (first-min).
    // Uniform LDS address -> ds_read broadcast, conflict-free.
    #pragma unroll 4
    for (int k = 0; k < K_CODES; k++) {
        const float4* cp = (const float4*)&cbs[8 * k];
        float4 cA = cp[0];
        float4 cB = cp[1];
        #pragma unroll
        for (int i = 0; i < PPT; i++) {
            float dot = __fmul_rn(xv[i][0], cA.x);
            dot = __fmaf_rn(xv[i][1], cA.y, dot);
            dot = __fmaf_rn(xv[i][2], cA.z, dot);
            dot = __fmaf_rn(xv[i][3], cA.w, dot);
            dot = __fmaf_rn(xv[i][4], cB.x, dot);
            float dist = __fadd_rn(__fsub_rn(xsq[i], __fadd_rn(dot, dot)), cB.y);
            if (dist < best[i]) { best[i] = dist; bidx[i] = k; }
        }
    }

    // ---- gather selected codewords, coalesced float4 stores; local loss ----
    float qr[PPT][D_DIM];
    float ls = 0.f;
    #pragma unroll
    for (int i = 0; i < PPT; i++) {
        const float* c = &cbs[8 * bidx[i]];
        #pragma unroll
        for (int d = 0; d < D_DIM; d++) {
            float qv = c[d];
            qr[i][d] = qv;
            float df = xv[i][d] - qv;
            ls += df * df;
        }
    }
    float* op = out + (b * D_DIM) * T_DIM + t;
    #pragma unroll
    for (int d = 0; d < D_DIM; d++) {
        float4 o;
        o.x = qr[0][d]; o.y = qr[1][d]; o.z = qr[2][d]; o.w = qr[3][d];
        *(float4*)(op + d * T_DIM) = o;   // straight-through output == q
    }

    // ---- block loss reduction -> one slot per block (no atomics/init) ----
    #pragma unroll
    for (int off = 32; off > 0; off >>= 1) ls += __shfl_down(ls, off, 64);
    __shared__ float wsum[BLK / 64];
    int lane = threadIdx.x & 63;
    int wid = threadIdx.x >> 6;
    if (lane == 0) wsum[wid] = ls;
    __syncthreads();
    if (threadIdx.x == 0) {
        float tot = 0.f;
        #pragma unroll
        for (int w = 0; w < BLK / 64; w++) tot += wsum[w];
        partials[blockIdx.x] = (double)tot;  // slot overwritten every launch
    }
}

__global__ __launch_bounds__(NBLOCKS) void vq_finalize(
        const double* __restrict__ partials, float* __restrict__ out) {
    double v = partials[threadIdx.x];   // 512 threads, one slot each
    #pragma unroll
    for (int off = 32; off > 0; off >>= 1) v += __shfl_down(v, off, 64);
    __shared__ double wsum[NBLOCKS / 64];
    int lane = threadIdx.x & 63;
    int wid = threadIdx.x >> 6;
    if (lane == 0) wsum[wid] = v;
    __syncthreads();
    if (threadIdx.x == 0) {
        double tot = 0.0;
        #pragma unroll
        for (int w = 0; w < NBLOCKS / 64; w++) tot += wsum[w];
        float loss = (float)(tot / (double)NELEM);
        out[NELEM] = loss;      // dictionary_loss
        out[NELEM + 1] = loss;  // commitment_loss (identical forward value)
    }
}

extern "C" void kernel_launch(void* const* d_in, const int* in_sizes, int n_in,
                              void* d_out, int out_size, void* d_ws, size_t ws_size,
                              hipStream_t stream) {
    const float* x = (const float*)d_in[0];   // fp32 (B,D,T)
    const float* e = (const float*)d_in[1];   // fp32 (D,K)
    float* out = (float*)d_out;               // fp32: quantized + 2 losses
    double* partials = (double*)d_ws;         // 512 × 8 B

    vq_main<<<NBLOCKS, BLK, 0, stream>>>(x, e, out, partials);
    vq_finalize<<<1, NBLOCKS, 0, stream>>>(partials, out);
}